// Round 1
// 953.537 us; speedup vs baseline: 1.0038x; 1.0038x over previous
//
#include <hip/hip_runtime.h>

typedef unsigned short u16;
typedef __bf16 bf16x8 __attribute__((ext_vector_type(8)));
typedef float f32x4 __attribute__((ext_vector_type(4)));

static __device__ __forceinline__ f32x4 mfma16(bf16x8 a, bf16x8 b, f32x4 c) {
  return __builtin_amdgcn_mfma_f32_16x16x32_bf16(a, b, c, 0, 0, 0);
}

static __device__ __forceinline__ u16 f2bf(float f) {
  union { float f; unsigned u; } v; v.f = f;
  unsigned r = v.u + 0x7fffu + ((v.u >> 16) & 1u);
  return (u16)(r >> 16);
}

// ---------------- mask element-size probe ----------------
__global__ void k_flag(const unsigned char* __restrict__ m, int* flag) {
  int t = threadIdx.x;  // 64 threads
  unsigned v = (unsigned)m[4*t+1] | (unsigned)m[4*t+2] | (unsigned)m[4*t+3];
  unsigned long long any = __ballot(v != 0);
  if (t == 0) *flag = (any == 0ull) ? 1 : 0;
}

// ---------------- mask bit-pack: elem -> 1 bit ----------------
__global__ __launch_bounds__(256) void k_pack(const void* __restrict__ m,
                                              const int* __restrict__ flagp,
                                              unsigned* __restrict__ out) {
  int flag = *flagp;
  int lane = threadIdx.x & 63, wv = threadIdx.x >> 6;
  long base = (long)blockIdx.x * 2048 + wv * 64 + lane;
#pragma unroll
  for (int it = 0; it < 8; ++it) {
    long elem = base + it * 256;
    bool pred = flag ? (((const int*)m)[elem] != 0)
                     : (((const unsigned char*)m)[elem] != 0);
    unsigned long long bal = __ballot(pred);
    if (lane == 0)  out[elem >> 5] = (unsigned)bal;
    if (lane == 32) out[elem >> 5] = (unsigned)(bal >> 32);
  }
}

// ---------------- weight transpose+convert: W[d][e] -> Wt[e][d] bf16 ----------------
__global__ __launch_bounds__(256) void k_wtr(const float* __restrict__ Wq,
                                             const float* __restrict__ Wk,
                                             const float* __restrict__ Wv,
                                             u16* __restrict__ Wt) {
  int m = blockIdx.z;
  const float* src = (m < 12) ? (Wq + (size_t)m * 65536)
                   : (m < 24) ? (Wk + (size_t)(m - 12) * 65536)
                              : (Wv + (size_t)(m - 24) * 65536);
  u16* dst = Wt + (size_t)m * 65536;
  __shared__ float T[64][65];
  int t = threadIdx.x;
  int d0 = blockIdx.x * 64, e0 = blockIdx.y * 64;
  for (int it = 0; it < 16; ++it) {
    int idx = it * 256 + t; int r = idx >> 6, c = idx & 63;
    T[r][c] = src[(size_t)(d0 + r) * 256 + e0 + c];
  }
  __syncthreads();
  for (int it = 0; it < 16; ++it) {
    int idx = it * 256 + t; int r = idx >> 6, c = idx & 63;
    dst[(size_t)(e0 + r) * 256 + d0 + c] = f2bf(T[c][r]);
  }
}

// ---------------- fp32 -> bf16 convert (+ optional fp32 copy) ----------------
__global__ __launch_bounds__(256) void k_cvt(const float* __restrict__ src,
                                             u16* __restrict__ db,
                                             float* dstf, long n) {
  long i = ((long)blockIdx.x * 256 + threadIdx.x) * 4;
  if (i >= n) return;
  float4 v = *(const float4*)(src + i);
  union { u16 u[4]; uint2 q; } o;
  o.u[0] = f2bf(v.x); o.u[1] = f2bf(v.y); o.u[2] = f2bf(v.z); o.u[3] = f2bf(v.w);
  *(uint2*)(db + i) = o.q;
  if (dstf) *(float4*)(dstf + i) = v;
}

// ---------------- fused 3-linear chain body (identical math to R2 k_gemm3) ----------------
template<int MODE>
static __device__ __forceinline__ void gemm3_body(
    const u16* __restrict__ X, const u16* __restrict__ Wt,
    const float* __restrict__ bias, u16* __restrict__ out, int Nk,
    long row0, u16 (*Xs)[264], u16 (*Ws)[40]) {
  int t = threadIdx.x, lane = t & 63, w = t >> 6, g = lane >> 4, li = lane & 15;

  for (int it = 0; it < 8; ++it) {
    int c = it * 256 + t, r = c >> 5, k8 = (c & 31) << 3;
    *(uint4*)&Xs[r][k8] = *(const uint4*)&X[(row0 + r) * 256 + k8];
  }

  for (int j = 0; j < 3; ++j) {
    f32x4 acc[4][4];
#pragma unroll
    for (int i = 0; i < 4; ++i)
#pragma unroll
      for (int jj = 0; jj < 4; ++jj) acc[i][jj] = (f32x4){0.f, 0.f, 0.f, 0.f};
    const u16* Wj = Wt + j * 65536;
    for (int kk = 0; kk < 8; ++kk) {
#pragma unroll
      for (int it = 0; it < 4; ++it) {
        int c = it * 256 + t, n = c >> 2, p = c & 3;
        *(uint4*)&Ws[n][p << 3] = *(const uint4*)&Wj[n * 256 + kk * 32 + (p << 3)];
      }
      __syncthreads();
      bf16x8 xf[4], wf[4];
#pragma unroll
      for (int f = 0; f < 4; ++f) xf[f] = *(const bf16x8*)&Xs[f * 16 + li][kk * 32 + g * 8];
#pragma unroll
      for (int f = 0; f < 4; ++f) wf[f] = *(const bf16x8*)&Ws[w * 64 + f * 16 + li][g * 8];
#pragma unroll
      for (int i = 0; i < 4; ++i)
#pragma unroll
        for (int jj = 0; jj < 4; ++jj)
          acc[i][jj] = (MODE == 0) ? mfma16(xf[i], wf[jj], acc[i][jj])
                                   : mfma16(wf[i], xf[jj], acc[i][jj]);
      __syncthreads();
    }
    if (j < 2) {
#pragma unroll
      for (int i = 0; i < 4; ++i)
#pragma unroll
        for (int jj = 0; jj < 4; ++jj)
#pragma unroll
          for (int r = 0; r < 4; ++r) {
            int R, C;
            if (MODE == 0) { R = i * 16 + g * 4 + r; C = w * 64 + jj * 16 + li; }
            else           { R = jj * 16 + li;       C = w * 64 + i * 16 + g * 4 + r; }
            Xs[R][C] = f2bf(acc[i][jj][r] + bias[j * 256 + C]);
          }
      __syncthreads();
    } else {
      if (MODE == 0) {
#pragma unroll
        for (int i = 0; i < 4; ++i)
#pragma unroll
          for (int jj = 0; jj < 4; ++jj)
#pragma unroll
            for (int r = 0; r < 4; ++r) {
              int R = i * 16 + g * 4 + r, C = w * 64 + jj * 16 + li;
              out[(row0 + R) * 256 + C] = f2bf(acc[i][jj][r] + bias[512 + C]);
            }
      } else {
        long b = row0 / Nk, rb = row0 - b * Nk;
#pragma unroll
        for (int i = 0; i < 4; ++i)
#pragma unroll
          for (int jj = 0; jj < 4; ++jj)
#pragma unroll
            for (int r = 0; r < 4; ++r) {
              int e = w * 64 + i * 16 + g * 4 + r, xr = jj * 16 + li;
              out[(b * 256 + e) * (long)Nk + rb + xr] = f2bf(acc[i][jj][r] + bias[512 + e]);
            }
      }
    }
  }
}

// One dispatch per layer: blocks [0,256) = Q-proj, [256,256+Mkv) = K-proj,
// [256+Mkv, 256+2*Mkv) = V-proj (transposed-out). 2-3 blocks/CU of independent
// roles co-resident -> barrier/latency stalls of one block hide under another.
__global__ __launch_bounds__(256, 2) void k_gemm3f(
    const u16* __restrict__ Xq, const u16* __restrict__ Xkv,
    const u16* __restrict__ Wt, const float* __restrict__ bq,
    const float* __restrict__ bk, const float* __restrict__ bv,
    u16* __restrict__ Qb, u16* __restrict__ Kb, u16* __restrict__ Vt,
    int layer, int Mkv, int Nk) {
  __shared__ __align__(16) u16 Xs[64][264];
  __shared__ __align__(16) u16 Ws[256][40];
  int u = blockIdx.x;
  if (u < 256)
    gemm3_body<0>(Xq, Wt + (size_t)layer * 3 * 65536, bq + layer * 768, Qb, 0,
                  (long)u * 64, Xs, Ws);
  else if (u < 256 + Mkv)
    gemm3_body<0>(Xkv, Wt + (size_t)(12 + layer * 3) * 65536, bk + layer * 768, Kb, 0,
                  (long)(u - 256) * 64, Xs, Ws);
  else
    gemm3_body<1>(Xkv, Wt + (size_t)(24 + layer * 3) * 65536, bv + layer * 768, Vt, Nk,
                  (long)(u - 256 - Mkv) * 64, Xs, Ws);
}

// ---------------- flash attention v2: 32-q blocks, grid 512, 2 blocks/CU ----------------
// Block = 32 q-rows, 512 threads, 8 waves: w -> (qg = w>>2, h = (w>>1)&1, s = w&1).
// s-group stages its own K/V k-half; wave computes S[16q x 16k(h)] of half s, then
// O[16q x 128d(h)] partial over half s. Epilogue merges s-partials in LDS.
// LDS 72064 B (< 80 KiB) -> 2 blocks/CU; V stored as 4 skewed planes [4][257][8]
// (conflict-free b128 on both staging write and PV read).
__global__ __launch_bounds__(512, 4) void k_attn(
    const u16* __restrict__ Qb, const u16* __restrict__ Kb, const u16* __restrict__ Vt,
    const unsigned* __restrict__ Mb,
    const float* __restrict__ gamma, const float* __restrict__ beta,
    float* xres, u16* xbout,
    const float* __restrict__ future, float* __restrict__ dout, int last, int Nk) {
  __shared__ __align__(16) char RAW[72064];
  u16 (*Qs)[264]        = (u16(*)[264])RAW;                    // [32][264] (prologue)
  u16 (*KsA)[32][264]   = (u16(*)[32][264])RAW;                // [2][32][264] (loop)
  u16 (*VsA)[4][257][8] = (u16(*)[4][257][8])(RAW + 33792);    // [2][4][257][8]
  u16 (*PsA)[2][16][40] = (u16(*)[2][16][40])(RAW + 66688);    // [s][qg][16][40]
  unsigned (*MskA)[32]  = (unsigned(*)[32])(RAW + 71808);      // [2][32]
  float* LredP = (float*)(RAW + 66688);          // [8][16] (aliases Ps, epilogue)
  float* SredP = (float*)(RAW + 66688 + 512);    // [4][16]
  float* QredP = (float*)(RAW + 66688 + 768);    // [4][16]
  float* mrgF  = (float*)RAW;                    // [64][132] (aliases Ks, epilogue)

  int t = threadIdx.x, lane = t & 63, w = t >> 6;
  int qg = w >> 2, h = (w >> 1) & 1, s = w & 1;
  int g = lane >> 4, li = lane & 15;
  int gl = (w >> 1) * 64 + lane;   // 0..255, unique within s-group

  // XCD-bijective swizzle: XCD x owns batches {2x, 2x+1} entirely -> its K/V
  // working set (<=4 MB) stays in that XCD's L2.
  int n = blockIdx.x;
  int b = ((n & 7) << 1) | ((n >> 8) & 1);
  int q0 = ((n >> 3) & 31) << 5;

  int W = Nk >> 5, iters = Nk >> 6, soff = s * (Nk >> 1);

  const u16* Qg = Qb + ((long)b * 1024 + q0) * 256;
  const u16* Kg = Kb + ((long)b * Nk + soff) * 256;
  const u16* Vg = Vt + (long)b * 256 * (long)Nk + soff;
  const unsigned* Mg = Mb + ((long)b * 1024 + q0) * (long)W + s * (Nk >> 6);

  // ---- prologue: stage Q, load Q fragments to registers ----
#pragma unroll
  for (int it = 0; it < 2; ++it) {
    int idx = it * 512 + t, r = idx >> 5, c = (idx & 31) << 3;
    *(uint4*)&Qs[r][c] = *(const uint4*)&Qg[(long)r * 256 + c];
  }
  __syncthreads();
  bf16x8 qf[8];
#pragma unroll
  for (int kc = 0; kc < 8; ++kc)
    qf[kc] = *(const bf16x8*)&Qs[qg * 16 + li][kc * 32 + g * 8];

  f32x4 O[8];
#pragma unroll
  for (int df = 0; df < 8; ++df) O[df] = (f32x4){0.f, 0.f, 0.f, 0.f};
  float l_l[4] = {0.f, 0.f, 0.f, 0.f};

  for (int ki = 0; ki < iters; ++ki) {
    int kb = ki << 5;
    __syncthreads();   // prev tile LDS reads (or qf loads) complete
#pragma unroll
    for (int it = 0; it < 4; ++it) {
      int idx = it * 256 + gl, r = idx >> 5, c = (idx & 31) << 3;
      *(uint4*)&KsA[s][r][c] = *(const uint4*)&Kg[(long)(kb + r) * 256 + c];
    }
#pragma unroll
    for (int it = 0; it < 4; ++it) {
      int idx = it * 256 + gl, d = idx >> 2, p = idx & 3;
      *(uint4*)&VsA[s][p][d][0] = *(const uint4*)&Vg[(long)d * Nk + kb + (p << 3)];
    }
    if (gl < 32) MskA[s][gl] = Mg[(long)gl * W + ki];
    __syncthreads();   // staging visible

    // QK^T: S[16q x 16k], k-half h of split s; 8 MFMA from 8 K reads
    f32x4 s0 = (f32x4){0.f, 0.f, 0.f, 0.f};
#pragma unroll
    for (int kc = 0; kc < 8; ++kc) {
      bf16x8 kf = *(const bf16x8*)&KsA[s][h * 16 + li][kc * 32 + g * 8];
      s0 = mfma16(qf[kc], kf, s0);
    }
#pragma unroll
    for (int r = 0; r < 4; ++r) {
      int qr = g * 4 + r;
      unsigned mw = MskA[s][qg * 16 + qr];
      bool km = (mw >> (h * 16 + li)) & 1u;
      float e = km ? 0.f : __expf(s0[r] * 0.0625f);
      l_l[r] += e;
      PsA[s][qg][qr][h * 16 + li] = f2bf(e);
    }
    __syncthreads();   // both h-halves of P visible
    // PV: O[16q x 128d(h)] over this 32-k tile; 8 MFMA from 8 V + 1 P read
    bf16x8 pa = *(const bf16x8*)&PsA[s][qg][li][g * 8];
#pragma unroll
    for (int df = 0; df < 8; ++df) {
      bf16x8 bv = *(const bf16x8*)&VsA[s][g][h * 128 + df * 16 + li][0];
      O[df] = mfma16(pa, bv, O[df]);
    }
  }

  // ---- epilogue: merge s-partials in LDS, LayerNorm, +residual ----
  __syncthreads();   // B1: loop LDS reads done
#pragma unroll
  for (int r = 0; r < 4; ++r) {
    float sv = l_l[r];
    sv += __shfl_xor(sv, 1); sv += __shfl_xor(sv, 2);
    sv += __shfl_xor(sv, 4); sv += __shfl_xor(sv, 8);
    if (li == 0) LredP[(s * 4 + h * 2 + qg) * 16 + g * 4 + r] = sv;
  }
  if (s == 1) {
#pragma unroll
    for (int df = 0; df < 8; ++df)
#pragma unroll
      for (int r = 0; r < 4; ++r) {
        int mr = (qg * 2 + h) * 16 + g * 4 + r;
        mrgF[mr * 132 + df * 16 + li] = O[df][r];
      }
  }
  __syncthreads();   // B2
  if (s == 0) {
    float rl[4];
#pragma unroll
    for (int r = 0; r < 4; ++r) {
      int qr = g * 4 + r;
      float lt = LredP[(qg) * 16 + qr] + LredP[(2 + qg) * 16 + qr]
               + LredP[(4 + qg) * 16 + qr] + LredP[(6 + qg) * 16 + qr];
      rl[r] = 1.f / fmaxf(lt, 1e-30f);
    }
    float sm[4] = {0.f, 0.f, 0.f, 0.f};
    float s2[4] = {0.f, 0.f, 0.f, 0.f};
#pragma unroll
    for (int df = 0; df < 8; ++df)
#pragma unroll
      for (int r = 0; r < 4; ++r) {
        int mr = (qg * 2 + h) * 16 + g * 4 + r;
        float y = (O[df][r] + mrgF[mr * 132 + df * 16 + li]) * rl[r];
        O[df][r] = y;
        sm[r] += y; s2[r] += y * y;
      }
#pragma unroll
    for (int r = 0; r < 4; ++r) {
      float a = sm[r], c = s2[r];
      a += __shfl_xor(a, 1); a += __shfl_xor(a, 2);
      a += __shfl_xor(a, 4); a += __shfl_xor(a, 8);
      c += __shfl_xor(c, 1); c += __shfl_xor(c, 2);
      c += __shfl_xor(c, 4); c += __shfl_xor(c, 8);
      if (li == 0) {
        SredP[(h * 2 + qg) * 16 + g * 4 + r] = a;
        QredP[(h * 2 + qg) * 16 + g * 4 + r] = c;
      }
    }
  }
  __syncthreads();   // B3
  if (s == 0) {
    float mu_[4], rstd_[4];
#pragma unroll
    for (int r = 0; r < 4; ++r) {
      int qr = g * 4 + r;
      float S = SredP[(qg) * 16 + qr] + SredP[(2 + qg) * 16 + qr];
      float Q2 = QredP[(qg) * 16 + qr] + QredP[(2 + qg) * 16 + qr];
      float m = S * (1.f / 256.f);
      mu_[r] = m;
      rstd_[r] = rsqrtf(Q2 * (1.f / 256.f) - m * m + 1e-5f);
    }
#pragma unroll
    for (int df = 0; df < 8; ++df) {
      int d = h * 128 + df * 16 + li;
      float gm = gamma[d], bt = beta[d];
#pragma unroll
      for (int r = 0; r < 4; ++r) {
        int q = q0 + qg * 16 + g * 4 + r;
        long idx = ((long)b * 1024 + q) * 256 + d;
        float o = (O[df][r] - mu_[r]) * rstd_[r] * gm + bt + xres[idx];
        if (last) dout[idx] = o + future[idx];
        else { xres[idx] = o; xbout[idx] = f2bf(o); }
      }
    }
  }
}

// ---------------- host ----------------
extern "C" void kernel_launch(void* const* d_in, const int* in_sizes, int n_in,
                              void* d_out, int out_size, void* d_ws, size_t ws_size,
                              hipStream_t stream) {
  const float* future  = (const float*)d_in[0];
  const float* history = (const float*)d_in[1];
  const float* graph   = (const float*)d_in[2];
  const void*  mask_hf = d_in[3];
  const void*  mask_fg = d_in[4];
  const float* Wq = (const float*)d_in[5];
  const float* bq = (const float*)d_in[6];
  const float* Wk = (const float*)d_in[7];
  const float* bk = (const float*)d_in[8];
  const float* Wv = (const float*)d_in[9];
  const float* bv = (const float*)d_in[10];
  const float* gamma = (const float*)d_in[11];
  const float* beta  = (const float*)d_in[12];
  float* dout = (float*)d_out;

  char* ws = (char*)d_ws;
  size_t off = 0;
  int* flag = (int*)(ws + off); off += 256;
  u16* Wt = (u16*)(ws + off);  off += (size_t)36 * 65536 * 2;
  u16* xb = (u16*)(ws + off);  off += (size_t)16384 * 256 * 2;
  float* x = (float*)(ws + off); off += (size_t)16384 * 256 * 4;
  u16* hb = (u16*)(ws + off);  off += (size_t)16384 * 256 * 2;
  u16* gb = (u16*)(ws + off);  off += (size_t)32768 * 256 * 2;
  u16* Qb = (u16*)(ws + off);  off += (size_t)16384 * 256 * 2;
  u16* Kb = (u16*)(ws + off);  off += (size_t)32768 * 256 * 2;
  u16* Vtb = (u16*)(ws + off); off += (size_t)32768 * 256 * 2;
  unsigned* Mbhf = (unsigned*)(ws + off); off += (size_t)16 * 1024 * 1024 / 8;
  unsigned* Mbfg = (unsigned*)(ws + off); off += (size_t)16 * 1024 * 2048 / 8;
  if (ws_size < off) return;

  k_flag<<<1, 64, 0, stream>>>((const unsigned char*)mask_hf, flag);
  k_pack<<<8192, 256, 0, stream>>>(mask_hf, flag, Mbhf);
  k_pack<<<16384, 256, 0, stream>>>(mask_fg, flag, Mbfg);
  k_wtr<<<dim3(4, 4, 36), 256, 0, stream>>>(Wq, Wk, Wv, Wt);
  k_cvt<<<4096, 256, 0, stream>>>(future, xb, x, 4194304L);
  k_cvt<<<4096, 256, 0, stream>>>(history, hb, nullptr, 4194304L);
  k_cvt<<<8192, 256, 0, stream>>>(graph, gb, nullptr, 8388608L);

  for (int i = 0; i < 4; ++i) {
    const u16* src = (i < 2) ? hb : gb;
    int Mkv = (i < 2) ? 256 : 512;
    int Nk = (i < 2) ? 1024 : 2048;
    const unsigned* mb = (i < 2) ? Mbhf : Mbfg;
    k_gemm3f<<<256 + 2 * Mkv, 256, 0, stream>>>(xb, src, Wt, bq, bk, bv,
                                                Qb, Kb, Vtb, i, Mkv, Nk);
    k_attn<<<512, 512, 0, stream>>>(Qb, Kb, Vtb, mb, gamma + i * 256, beta + i * 256,
                                    x, xb, future, dout, (i == 3) ? 1 : 0, Nk);
  }
}